// Round 1
// 940.039 us; speedup vs baseline: 1.0283x; 1.0283x over previous
//
#include <hip/hip_runtime.h>

#define N_TOK 2048
#define DMODEL 1024
#define NEXP 12
#define HS_DIM 2048
#define HR_DIM 3072

typedef __attribute__((ext_vector_type(8))) short bf16x8;
typedef __attribute__((ext_vector_type(16))) float f32x16;

#define AS1 __attribute__((address_space(1)))
#define AS3 __attribute__((address_space(3)))

__device__ __forceinline__ void gl_lds16(const void* g, void* l) {
  __builtin_amdgcn_global_load_lds((const AS1 void*)g, (AS3 void*)l, 16, 0, 0);
}

__device__ __forceinline__ unsigned short f2bf(float x) {
  union { float f; unsigned int u; } v; v.f = x;
  unsigned int u = v.u;
  u += 0x7fff + ((u >> 16) & 1);   // round-to-nearest-even
  return (unsigned short)(u >> 16);
}
__device__ __forceinline__ unsigned pack2(float a, float b) {
  return (unsigned)f2bf(a) | ((unsigned)f2bf(b) << 16);
}
__device__ __forceinline__ float gelu_exact(float x) {
  return 0.5f * x * (1.0f + erff(x * 0.70710678118654752f));
}

// ---------------- pre-pass: fp32 -> bf16 conversions ----------------

__global__ __launch_bounds__(256)
void convert_x_kernel(const float* __restrict__ X, unsigned short* __restrict__ XB) {
  const int idx = (blockIdx.x * 256 + threadIdx.x) * 8;
  float4 f0 = *(const float4*)(X + idx);
  float4 f1 = *(const float4*)(X + idx + 4);
  uint4 o;
  o.x = pack2(f0.x, f0.y); o.y = pack2(f0.z, f0.w);
  o.z = pack2(f1.x, f1.y); o.w = pack2(f1.z, f1.w);
  *(uint4*)(XB + idx) = o;
}

// W [batch][K][N] fp32 -> WT [batch][N][K] bf16.  64x64 tiles via LDS.
__global__ __launch_bounds__(256)
void tconv_kernel(const float* __restrict__ W, unsigned short* __restrict__ WT,
                  int K, int N) {
  const int n0 = blockIdx.x * 64;
  const int k0 = blockIdx.y * 64;
  const size_t bo = (size_t)blockIdx.z * K * N;
  __shared__ __align__(16) unsigned short Ts[64 * 72];
  const int t = threadIdx.x;
  const int k4 = (t >> 4) * 4, n4 = (t & 15) * 4;
  float4 rw[4];
#pragma unroll
  for (int i = 0; i < 4; ++i)
    rw[i] = *(const float4*)(W + bo + (size_t)(k0 + k4 + i) * N + n0 + n4);
#pragma unroll
  for (int j = 0; j < 4; ++j) {
    uint2 v;
    v.x = pack2(((const float*)&rw[0])[j], ((const float*)&rw[1])[j]);
    v.y = pack2(((const float*)&rw[2])[j], ((const float*)&rw[3])[j]);
    *(uint2*)&Ts[(n4 + j) * 72 + k4] = v;
  }
  __syncthreads();
  const int n = t >> 2, kc = (t & 3) * 16;
  uint4 v0 = *(const uint4*)&Ts[n * 72 + kc];
  uint4 v1 = *(const uint4*)&Ts[n * 72 + kc + 8];
  unsigned short* dst = WT + (size_t)blockIdx.z * N * K + (size_t)(n0 + n) * K + k0 + kc;
  *(uint4*)dst = v0;
  *(uint4*)(dst + 8) = v1;
}

// ---------------- routing ----------------

__global__ void init_kernel(int* counts, int* cursors) {
  int t = threadIdx.x;
  if (t < NEXP) { counts[t] = 0; cursors[t] = 0; }
}

__global__ __launch_bounds__(256)
void router_kernel(const float* __restrict__ X, const float* __restrict__ Wr,
                   const float* __restrict__ br, int* __restrict__ top_e,
                   float* __restrict__ top_w, int* __restrict__ counts) {
  const int wv = threadIdx.x >> 6, lane = threadIdx.x & 63;
  const int n = blockIdx.x * 4 + wv;
  float a[NEXP];
#pragma unroll
  for (int e = 0; e < NEXP; ++e) a[e] = 0.f;
  for (int it = 0; it < DMODEL / 64; ++it) {
    int k = it * 64 + lane;
    float xv = X[(size_t)n * DMODEL + k];
    const float* wr = Wr + (size_t)k * NEXP;
#pragma unroll
    for (int e = 0; e < NEXP; ++e) a[e] += xv * wr[e];
  }
#pragma unroll
  for (int e = 0; e < NEXP; ++e)
    for (int o = 32; o > 0; o >>= 1) a[e] += __shfl_xor(a[e], o, 64);
  if (lane == 0) {
    float l[NEXP];
#pragma unroll
    for (int e = 0; e < NEXP; ++e) l[e] = (a[e] + br[e]) * (1.0f / 1.5f);
    int e0 = 0;
    for (int e = 1; e < NEXP; ++e) if (l[e] > l[e0]) e0 = e;
    int e1 = (e0 == 0) ? 1 : 0;
    for (int e = 0; e < NEXP; ++e) if (e != e0 && l[e] > l[e1]) e1 = e;
    float w0 = 1.f / (1.f + expf(l[e1] - l[e0]));
    top_e[n * 2 + 0] = e0; top_e[n * 2 + 1] = e1;
    top_w[n * 2 + 0] = w0; top_w[n * 2 + 1] = 1.f - w0;
    atomicAdd(&counts[e0], 1); atomicAdd(&counts[e1], 1);
  }
}

__global__ void scan_kernel(const int* __restrict__ counts, int* __restrict__ offs) {
  if (threadIdx.x == 0) {
    int s = 0;
    for (int e = 0; e < NEXP; ++e) { offs[e] = s; s += counts[e]; }
    offs[NEXP] = s;
  }
}

__global__ __launch_bounds__(256)
void fill_kernel(const int* __restrict__ top_e, const float* __restrict__ top_w,
                 const int* __restrict__ offs, int* __restrict__ cursors,
                 int* __restrict__ slot_tok, float* __restrict__ slot_w) {
  int n = blockIdx.x * 256 + threadIdx.x;
  if (n >= N_TOK) return;
#pragma unroll
  for (int j = 0; j < 2; ++j) {
    int e = top_e[n * 2 + j];
    int p = atomicAdd(&cursors[e], 1);
    int s = offs[e] + p;
    slot_tok[s] = n;
    slot_w[s] = top_w[n * 2 + j];
  }
}

__global__ __launch_bounds__(256)
void zero_out_kernel(float4* __restrict__ out) {
  out[blockIdx.x * 256 + threadIdx.x] = make_float4(0.f, 0.f, 0.f, 0.f);
}

// ---------------- GEMM1 + GEGLU, single launch (shared + all experts) ----
// BM=128, BN=128 act-cols (B panel = 256 rows: a-cols then g-cols).
// BK=64 as two contiguous BK=32 sub-buffers. mfma_f32_32x32x16_bf16.
// Wave owns 64x64 of both a and g; GEGLU in-register.
#define G1_SHARED 256   /* 16 m x 16 n */
#define G1_PER_E  384   /* 16 m x 24 n */

__global__ __launch_bounds__(256, 2)
void gemm1_all_kernel(const unsigned short* __restrict__ XB,
                      const unsigned short* __restrict__ WS,
                      const unsigned short* __restrict__ WE,
                      const float* __restrict__ BSb, const float* __restrict__ BEb,
                      unsigned short* __restrict__ ACT_S, unsigned short* __restrict__ ACT_R,
                      const int* __restrict__ slot_tok, const int* __restrict__ offs,
                      const int* __restrict__ counts) {
  int id = blockIdx.x;
  const unsigned short* W; const float* bias; unsigned short* ACT;
  int H, count, off, m0, n0, routed;
  if (id < G1_SHARED) {
    routed = 0;
    m0 = (id >> 4) * 128; n0 = (id & 15) * 128;
    W = WS; bias = BSb; ACT = ACT_S; H = HS_DIM; count = N_TOK; off = 0;
  } else {
    routed = 1;
    id -= G1_SHARED;
    const int e = id / G1_PER_E, rem = id % G1_PER_E;
    m0 = (rem / 24) * 128; n0 = (rem % 24) * 128;
    W = WE + (size_t)e * 2 * HR_DIM * DMODEL;
    bias = BEb + (size_t)e * 2 * HR_DIM;
    ACT = ACT_R; H = HR_DIM; count = counts[e]; off = offs[e];
  }
  if (m0 >= count) return;

  __shared__ __align__(16) unsigned short As[2 * 4096];    // 16 KB
  __shared__ __align__(16) unsigned short Bs[2 * 8192];    // 32 KB

  const int t = threadIdx.x;
  const int lane = t & 63, wv = t >> 6;
  const int srow = t >> 2, skc = t & 3;
  const int ln31 = lane & 31, hi = lane >> 5;
  const int wr = wv >> 1, wc = wv & 1;

  // A source rows (2 groups of 64)
  const unsigned short* ap[2];
#pragma unroll
  for (int g = 0; g < 2; ++g) {
    int mr = m0 + srow + 64 * g;
    int tok;
    if (routed) {
      int s = off + (mr < count ? mr : count - 1);
      tok = slot_tok[s];
    } else {
      tok = mr;
    }
    ap[g] = XB + (size_t)tok * DMODEL + skc * 8;
  }
  // B source rows (4 groups of 64; groups 0-1 = a-cols, 2-3 = g-cols)
  const unsigned short* bp[4];
#pragma unroll
  for (int g = 0; g < 4; ++g) {
    int brow = srow + 64 * g;
    int wrow = (brow < 128) ? (n0 + brow) : (H + n0 + brow - 128);
    bp[g] = W + (size_t)wrow * DMODEL + skc * 8;
  }

  f32x16 acc_a[2][2], acc_g[2][2];
  const f32x16 z16 = {0.f,0.f,0.f,0.f,0.f,0.f,0.f,0.f,0.f,0.f,0.f,0.f,0.f,0.f,0.f,0.f};
#pragma unroll
  for (int i = 0; i < 2; ++i)
#pragma unroll
    for (int j = 0; j < 2; ++j) { acc_a[i][j] = z16; acc_g[i][j] = z16; }

  for (int kt = 0; kt < DMODEL / 64; ++kt) {
    const int kb = kt * 64;
    __syncthreads();
#pragma unroll
    for (int h = 0; h < 2; ++h) {
#pragma unroll
      for (int g = 0; g < 2; ++g)
        gl_lds16(ap[g] + kb + h * 32, &As[h * 4096 + g * 2048 + wv * 512]);
#pragma unroll
      for (int g = 0; g < 4; ++g)
        gl_lds16(bp[g] + kb + h * 32, &Bs[h * 8192 + g * 2048 + wv * 512]);
    }
    __syncthreads();
#pragma unroll
    for (int ks = 0; ks < 4; ++ks) {
      const int h = ks >> 1;
      const int ko = (ks & 1) * 16 + hi * 8;
      bf16x8 aF[2], bA[2], bG[2];
#pragma unroll
      for (int i = 0; i < 2; ++i)
        aF[i] = *(const bf16x8*)&As[h * 4096 + (wr * 64 + i * 32 + ln31) * 32 + ko];
#pragma unroll
      for (int j = 0; j < 2; ++j) {
        bA[j] = *(const bf16x8*)&Bs[h * 8192 + (wc * 64 + j * 32 + ln31) * 32 + ko];
        bG[j] = *(const bf16x8*)&Bs[h * 8192 + (128 + wc * 64 + j * 32 + ln31) * 32 + ko];
      }
#pragma unroll
      for (int i = 0; i < 2; ++i)
#pragma unroll
        for (int j = 0; j < 2; ++j) {
          acc_a[i][j] = __builtin_amdgcn_mfma_f32_32x32x16_bf16(aF[i], bA[j], acc_a[i][j], 0, 0, 0);
          acc_g[i][j] = __builtin_amdgcn_mfma_f32_32x32x16_bf16(aF[i], bG[j], acc_g[i][j], 0, 0, 0);
        }
    }
  }

  float ba[2], bg[2];
#pragma unroll
  for (int j = 0; j < 2; ++j) {
    int col = n0 + wc * 64 + j * 32 + ln31;
    ba[j] = bias[col];
    bg[j] = bias[H + col];
  }
#pragma unroll
  for (int i = 0; i < 2; ++i)
#pragma unroll
    for (int j = 0; j < 2; ++j)
#pragma unroll
      for (int reg = 0; reg < 16; ++reg) {
        // 32x32 C/D: col = lane&31, row = (reg&3) + 8*(reg>>2) + 4*(lane>>5)
        int row = wr * 64 + i * 32 + (reg & 3) + 8 * (reg >> 2) + 4 * hi;
        if (m0 + row < count) {
          int col = n0 + wc * 64 + j * 32 + ln31;
          float av = acc_a[i][j][reg] + ba[j];
          float gv = acc_g[i][j][reg] + bg[j];
          ACT[(size_t)(off + m0 + row) * H + col] = f2bf(av * gelu_exact(gv));
        }
      }
}

// ---------------- GEMM2, single launch (shared + routed), atomic combine ---
// Split-K: uniform 1024-deep K-chunks (shared K=2048 -> 2 splits,
// routed K=3072 -> 3 splits). Bias added only by the kc==0 split.
// Rationale: pre-split only ~416 blocks were active (1.6/CU) -> the
// 2-barrier K-loop's vmcnt(0) drain was unhidden (MfmaUtil 7.4%, HBM 13%).
#define G2_SHARED 256   /* 16 m x 8 n x 2 ksplit */
#define G2_PER_E  384   /* 16 m x 8 n x 3 ksplit */
#define G2_KCHUNK 1024

__global__ __launch_bounds__(256, 2)
void gemm2_all_kernel(const unsigned short* __restrict__ ACT_S,
                      const unsigned short* __restrict__ ACT_R,
                      const unsigned short* __restrict__ WSt,
                      const unsigned short* __restrict__ WEt,
                      const float* __restrict__ BSb, const float* __restrict__ BEb,
                      float* __restrict__ OUT,
                      const int* __restrict__ slot_tok, const float* __restrict__ slot_w,
                      const int* __restrict__ offs, const int* __restrict__ counts) {
  int id = blockIdx.x;
  const unsigned short* A; const unsigned short* W; const float* bias;
  int K, count, off, m0, n0, routed, kc;
  if (id < G2_SHARED) {
    routed = 0;
    kc = id & 1;
    const int rem2 = id >> 1;
    m0 = (rem2 >> 3) * 128; n0 = (rem2 & 7) * 128;
    A = ACT_S; W = WSt; bias = BSb; K = HS_DIM; count = N_TOK; off = 0;
  } else {
    routed = 1;
    id -= G2_SHARED;
    const int e = id / G2_PER_E, rem = id % G2_PER_E;
    kc = rem % 3;
    const int rem2 = rem / 3;
    m0 = (rem2 >> 3) * 128; n0 = (rem2 & 7) * 128;
    A = ACT_R; W = WEt + (size_t)e * DMODEL * HR_DIM;
    bias = BEb + (size_t)e * DMODEL; K = HR_DIM; count = counts[e]; off = offs[e];
  }
  if (m0 >= count) return;

  __shared__ __align__(16) unsigned short As[2 * 4096];    // 16 KB
  __shared__ __align__(16) unsigned short Bs[2 * 4096];    // 16 KB

  const int t = threadIdx.x;
  const int lane = t & 63, wv = t >> 6;
  const int srow = t >> 2, skc = t & 3;
  const int ln31 = lane & 31, hi = lane >> 5;
  const int wr = wv >> 1, wc = wv & 1;

  const unsigned short* ap[2];
#pragma unroll
  for (int g = 0; g < 2; ++g) {
    int mr = m0 + srow + 64 * g;
    int r = off + (mr < count ? mr : count - 1);
    ap[g] = A + (size_t)r * K + skc * 8;
  }
  const unsigned short* bp[2];
#pragma unroll
  for (int g = 0; g < 2; ++g)
    bp[g] = W + (size_t)(n0 + srow + 64 * g) * K + skc * 8;

  f32x16 acc[2][2];
  const f32x16 z16 = {0.f,0.f,0.f,0.f,0.f,0.f,0.f,0.f,0.f,0.f,0.f,0.f,0.f,0.f,0.f,0.f};
#pragma unroll
  for (int i = 0; i < 2; ++i)
#pragma unroll
    for (int j = 0; j < 2; ++j) acc[i][j] = z16;

  const int kt0 = kc * (G2_KCHUNK >> 6);
  const int kt1 = kt0 + (G2_KCHUNK >> 6);
  for (int kt = kt0; kt < kt1; ++kt) {
    const int kb = kt * 64;
    __syncthreads();
#pragma unroll
    for (int h = 0; h < 2; ++h) {
#pragma unroll
      for (int g = 0; g < 2; ++g) {
        gl_lds16(ap[g] + kb + h * 32, &As[h * 4096 + g * 2048 + wv * 512]);
        gl_lds16(bp[g] + kb + h * 32, &Bs[h * 4096 + g * 2048 + wv * 512]);
      }
    }
    __syncthreads();
#pragma unroll
    for (int ks = 0; ks < 4; ++ks) {
      const int h = ks >> 1;
      const int ko = (ks & 1) * 16 + hi * 8;
      bf16x8 aF[2], bF[2];
#pragma unroll
      for (int i = 0; i < 2; ++i)
        aF[i] = *(const bf16x8*)&As[h * 4096 + (wr * 64 + i * 32 + ln31) * 32 + ko];
#pragma unroll
      for (int j = 0; j < 2; ++j)
        bF[j] = *(const bf16x8*)&Bs[h * 4096 + (wc * 64 + j * 32 + ln31) * 32 + ko];
#pragma unroll
      for (int i = 0; i < 2; ++i)
#pragma unroll
        for (int j = 0; j < 2; ++j)
          acc[i][j] = __builtin_amdgcn_mfma_f32_32x32x16_bf16(aF[i], bF[j], acc[i][j], 0, 0, 0);
    }
  }

  float bb[2];
#pragma unroll
  for (int j = 0; j < 2; ++j)
    bb[j] = (kc == 0) ? bias[n0 + wc * 64 + j * 32 + ln31] : 0.f;
#pragma unroll
  for (int i = 0; i < 2; ++i)
#pragma unroll
    for (int j = 0; j < 2; ++j)
#pragma unroll
      for (int reg = 0; reg < 16; ++reg) {
        int row = wr * 64 + i * 32 + (reg & 3) + 8 * (reg >> 2) + 4 * hi;
        if (m0 + row < count) {
          int col = n0 + wc * 64 + j * 32 + ln31;
          float v = acc[i][j][reg] + bb[j];
          if (routed) {
            int s = off + m0 + row;
            atomicAdd(&OUT[(size_t)slot_tok[s] * DMODEL + col], slot_w[s] * v);
          } else {
            atomicAdd(&OUT[(size_t)(m0 + row) * DMODEL + col], v);
          }
        }
      }
}

// ---------------- launch ----------------

extern "C" void kernel_launch(void* const* d_in, const int* in_sizes, int n_in,
                              void* d_out, int out_size, void* d_ws, size_t ws_size,
                              hipStream_t stream) {
  const float* x   = (const float*)d_in[0];
  const float* Ws1 = (const float*)d_in[1];
  const float* bs1 = (const float*)d_in[2];
  const float* Ws2 = (const float*)d_in[3];
  const float* bs2 = (const float*)d_in[4];
  const float* We1 = (const float*)d_in[5];
  const float* be1 = (const float*)d_in[6];
  const float* We2 = (const float*)d_in[7];
  const float* be2 = (const float*)d_in[8];
  const float* Wr  = (const float*)d_in[9];
  const float* br  = (const float*)d_in[10];
  float* out = (float*)d_out;

  char* p = (char*)d_ws;
  int* counts  = (int*)p; p += 256;
  int* cursors = (int*)p; p += 256;
  int* offs    = (int*)p; p += 256;
  int* top_e   = (int*)p; p += (size_t)N_TOK * 2 * 4;
  float* top_w = (float*)p; p += (size_t)N_TOK * 2 * 4;
  int* slot_tok = (int*)p; p += (size_t)2 * N_TOK * 4;
  float* slot_w = (float*)p; p += (size_t)2 * N_TOK * 4;
  unsigned short* xb    = (unsigned short*)p; p += (size_t)N_TOK * DMODEL * 2;
  unsigned short* ws1t  = (unsigned short*)p; p += (size_t)2 * HS_DIM * DMODEL * 2;
  unsigned short* ws2t  = (unsigned short*)p; p += (size_t)DMODEL * HS_DIM * 2;
  unsigned short* we1t  = (unsigned short*)p; p += (size_t)NEXP * 2 * HR_DIM * DMODEL * 2;
  unsigned short* we2t  = (unsigned short*)p; p += (size_t)NEXP * DMODEL * HR_DIM * 2;
  unsigned short* act_s = (unsigned short*)p; p += (size_t)N_TOK * HS_DIM * 2;
  unsigned short* act_r = (unsigned short*)p; p += (size_t)2 * N_TOK * HR_DIM * 2;

  zero_out_kernel<<<(N_TOK * DMODEL) / 1024, 256, 0, stream>>>((float4*)out);

  // conversions
  convert_x_kernel<<<(N_TOK * DMODEL) / 2048, 256, 0, stream>>>(x, xb);
  tconv_kernel<<<dim3(2 * HS_DIM / 64, DMODEL / 64, 1), 256, 0, stream>>>(Ws1, ws1t, DMODEL, 2 * HS_DIM);
  tconv_kernel<<<dim3(DMODEL / 64, HS_DIM / 64, 1), 256, 0, stream>>>(Ws2, ws2t, HS_DIM, DMODEL);
  tconv_kernel<<<dim3(2 * HR_DIM / 64, DMODEL / 64, NEXP), 256, 0, stream>>>(We1, we1t, DMODEL, 2 * HR_DIM);
  tconv_kernel<<<dim3(DMODEL / 64, HR_DIM / 64, NEXP), 256, 0, stream>>>(We2, we2t, HR_DIM, DMODEL);

  // routing chain
  init_kernel<<<1, 64, 0, stream>>>(counts, cursors);
  router_kernel<<<N_TOK / 4, 256, 0, stream>>>(x, Wr, br, top_e, top_w, counts);
  scan_kernel<<<1, 64, 0, stream>>>(counts, offs);
  fill_kernel<<<N_TOK / 256, 256, 0, stream>>>(top_e, top_w, offs, cursors, slot_tok, slot_w);

  // GEMM1 + GEGLU (shared + all experts, one launch)
  gemm1_all_kernel<<<G1_SHARED + G1_PER_E * NEXP, 256, 0, stream>>>(
      xb, ws1t, we1t, bs1, be1, act_s, act_r, slot_tok, offs, counts);

  // GEMM2 (shared + routed, one launch, split-K, atomic accumulate)
  gemm2_all_kernel<<<G2_SHARED + G2_PER_E * NEXP, 256, 0, stream>>>(
      act_s, act_r, ws2t, we2t, bs2, be2, out, slot_tok, slot_w, offs, counts);
}

// Round 2
// 890.397 us; speedup vs baseline: 1.0856x; 1.0558x over previous
//
#include <hip/hip_runtime.h>

#define N_TOK 2048
#define DMODEL 1024
#define NEXP 12
#define HS_DIM 2048
#define HR_DIM 3072
#define NSLOT (2 * N_TOK)   /* 4096 routed slots total */

typedef __attribute__((ext_vector_type(8))) short bf16x8;
typedef __attribute__((ext_vector_type(16))) float f32x16;

#define AS1 __attribute__((address_space(1)))
#define AS3 __attribute__((address_space(3)))

__device__ __forceinline__ void gl_lds16(const void* g, void* l) {
  __builtin_amdgcn_global_load_lds((const AS1 void*)g, (AS3 void*)l, 16, 0, 0);
}

__device__ __forceinline__ unsigned short f2bf(float x) {
  union { float f; unsigned int u; } v; v.f = x;
  unsigned int u = v.u;
  u += 0x7fff + ((u >> 16) & 1);   // round-to-nearest-even
  return (unsigned short)(u >> 16);
}
__device__ __forceinline__ unsigned pack2(float a, float b) {
  return (unsigned)f2bf(a) | ((unsigned)f2bf(b) << 16);
}
__device__ __forceinline__ float gelu_exact(float x) {
  return 0.5f * x * (1.0f + erff(x * 0.70710678118654752f));
}

// ---------------- pre-pass: fp32 -> bf16 conversions ----------------

__global__ __launch_bounds__(256)
void convert_x_kernel(const float* __restrict__ X, unsigned short* __restrict__ XB) {
  const int idx = (blockIdx.x * 256 + threadIdx.x) * 8;
  float4 f0 = *(const float4*)(X + idx);
  float4 f1 = *(const float4*)(X + idx + 4);
  uint4 o;
  o.x = pack2(f0.x, f0.y); o.y = pack2(f0.z, f0.w);
  o.z = pack2(f1.x, f1.y); o.w = pack2(f1.z, f1.w);
  *(uint4*)(XB + idx) = o;
}

// W [batch][K][N] fp32 -> WT [batch][N][K] bf16.  64x64 tiles via LDS.
__global__ __launch_bounds__(256)
void tconv_kernel(const float* __restrict__ W, unsigned short* __restrict__ WT,
                  int K, int N) {
  const int n0 = blockIdx.x * 64;
  const int k0 = blockIdx.y * 64;
  const size_t bo = (size_t)blockIdx.z * K * N;
  __shared__ __align__(16) unsigned short Ts[64 * 72];
  const int t = threadIdx.x;
  const int k4 = (t >> 4) * 4, n4 = (t & 15) * 4;
  float4 rw[4];
#pragma unroll
  for (int i = 0; i < 4; ++i)
    rw[i] = *(const float4*)(W + bo + (size_t)(k0 + k4 + i) * N + n0 + n4);
#pragma unroll
  for (int j = 0; j < 4; ++j) {
    uint2 v;
    v.x = pack2(((const float*)&rw[0])[j], ((const float*)&rw[1])[j]);
    v.y = pack2(((const float*)&rw[2])[j], ((const float*)&rw[3])[j]);
    *(uint2*)&Ts[(n4 + j) * 72 + k4] = v;
  }
  __syncthreads();
  const int n = t >> 2, kc = (t & 3) * 16;
  uint4 v0 = *(const uint4*)&Ts[n * 72 + kc];
  uint4 v1 = *(const uint4*)&Ts[n * 72 + kc + 8];
  unsigned short* dst = WT + (size_t)blockIdx.z * N * K + (size_t)(n0 + n) * K + k0 + kc;
  *(uint4*)dst = v0;
  *(uint4*)(dst + 8) = v1;
}

// ---------------- routing ----------------

__global__ void init_kernel(int* counts, int* cursors) {
  int t = threadIdx.x;
  if (t < NEXP) { counts[t] = 0; cursors[t] = 0; }
}

__global__ __launch_bounds__(256)
void router_kernel(const float* __restrict__ X, const float* __restrict__ Wr,
                   const float* __restrict__ br, int* __restrict__ top_e,
                   float* __restrict__ top_w, int* __restrict__ counts) {
  const int wv = threadIdx.x >> 6, lane = threadIdx.x & 63;
  const int n = blockIdx.x * 4 + wv;
  float a[NEXP];
#pragma unroll
  for (int e = 0; e < NEXP; ++e) a[e] = 0.f;
  for (int it = 0; it < DMODEL / 64; ++it) {
    int k = it * 64 + lane;
    float xv = X[(size_t)n * DMODEL + k];
    const float* wr = Wr + (size_t)k * NEXP;
#pragma unroll
    for (int e = 0; e < NEXP; ++e) a[e] += xv * wr[e];
  }
#pragma unroll
  for (int e = 0; e < NEXP; ++e)
    for (int o = 32; o > 0; o >>= 1) a[e] += __shfl_xor(a[e], o, 64);
  if (lane == 0) {
    float l[NEXP];
#pragma unroll
    for (int e = 0; e < NEXP; ++e) l[e] = (a[e] + br[e]) * (1.0f / 1.5f);
    int e0 = 0;
    for (int e = 1; e < NEXP; ++e) if (l[e] > l[e0]) e0 = e;
    int e1 = (e0 == 0) ? 1 : 0;
    for (int e = 0; e < NEXP; ++e) if (e != e0 && l[e] > l[e1]) e1 = e;
    float w0 = 1.f / (1.f + expf(l[e1] - l[e0]));
    top_e[n * 2 + 0] = e0; top_e[n * 2 + 1] = e1;
    top_w[n * 2 + 0] = w0; top_w[n * 2 + 1] = 1.f - w0;
    atomicAdd(&counts[e0], 1); atomicAdd(&counts[e1], 1);
  }
}

__global__ void scan_kernel(const int* __restrict__ counts, int* __restrict__ offs) {
  if (threadIdx.x == 0) {
    int s = 0;
    for (int e = 0; e < NEXP; ++e) { offs[e] = s; s += counts[e]; }
    offs[NEXP] = s;
  }
}

__global__ __launch_bounds__(256)
void fill_kernel(const int* __restrict__ top_e, const float* __restrict__ top_w,
                 const int* __restrict__ offs, int* __restrict__ cursors,
                 int* __restrict__ slot_tok, float* __restrict__ slot_w,
                 int* __restrict__ tok_slot) {
  int n = blockIdx.x * 256 + threadIdx.x;
  if (n >= N_TOK) return;
#pragma unroll
  for (int j = 0; j < 2; ++j) {
    int e = top_e[n * 2 + j];
    int p = atomicAdd(&cursors[e], 1);
    int s = offs[e] + p;
    slot_tok[s] = n;
    slot_w[s] = top_w[n * 2 + j];
    tok_slot[n * 2 + j] = s;
  }
}

// ---------------- GEMM1 + GEGLU, single launch (shared + all experts) ----
// BM=128, BN=128 act-cols (B panel = 256 rows: a-cols then g-cols).
// BK=32, double-buffered LDS, prefetch-next-before-compute (min 2-phase),
// raw s_barrier + asm vmcnt(0). LDS chunk XOR-swizzle (c ^ ((row>>1)&3))
// applied on the GLOBAL source (gl_lds16 dest must stay linear) and on the
// fragment-read side -> bank-conflict-free ds_read_b128.
#define G1_SHARED 256   /* 16 m x 16 n */
#define G1_PER_E  384   /* 16 m x 24 n */

__global__ __launch_bounds__(256, 2)
void gemm1_all_kernel(const unsigned short* __restrict__ XB,
                      const unsigned short* __restrict__ WS,
                      const unsigned short* __restrict__ WE,
                      const float* __restrict__ BSb, const float* __restrict__ BEb,
                      unsigned short* __restrict__ ACT_S, unsigned short* __restrict__ ACT_R,
                      const int* __restrict__ slot_tok, const int* __restrict__ offs,
                      const int* __restrict__ counts) {
  int id = blockIdx.x;
  const unsigned short* W; const float* bias; unsigned short* ACT;
  int H, count, off, m0, n0, routed;
  if (id < G1_SHARED) {
    routed = 0;
    m0 = (id >> 4) * 128; n0 = (id & 15) * 128;
    W = WS; bias = BSb; ACT = ACT_S; H = HS_DIM; count = N_TOK; off = 0;
  } else {
    routed = 1;
    id -= G1_SHARED;
    const int e = id / G1_PER_E, rem = id % G1_PER_E;
    m0 = (rem / 24) * 128; n0 = (rem % 24) * 128;
    W = WE + (size_t)e * 2 * HR_DIM * DMODEL;
    bias = BEb + (size_t)e * 2 * HR_DIM;
    ACT = ACT_R; H = HR_DIM; count = counts[e]; off = offs[e];
  }
  if (m0 >= count) return;

  // per buffer: A 128x32 shorts (8 KB), B 256x32 shorts (16 KB); x2 bufs = 48 KB
  __shared__ __align__(16) unsigned short As[2 * 4096];
  __shared__ __align__(16) unsigned short Bs[2 * 8192];

  const int t = threadIdx.x;
  const int lane = t & 63, wv = t >> 6;
  const int srow = t >> 2, skc = t & 3;
  const int ln31 = lane & 31, hi = lane >> 5;
  const int wr = wv >> 1, wc = wv & 1;
  const int skc_s = skc ^ ((srow >> 1) & 3);   // source-side chunk swizzle

  // A source rows (2 groups of 64)
  const unsigned short* ap[2];
#pragma unroll
  for (int g = 0; g < 2; ++g) {
    int mr = m0 + srow + 64 * g;
    int tok;
    if (routed) {
      int s = off + (mr < count ? mr : count - 1);
      tok = slot_tok[s];
    } else {
      tok = mr;
    }
    ap[g] = XB + (size_t)tok * DMODEL + skc_s * 8;
  }
  // B source rows (4 groups of 64; groups 0-1 = a-cols, 2-3 = g-cols)
  const unsigned short* bp[4];
#pragma unroll
  for (int g = 0; g < 4; ++g) {
    int brow = srow + 64 * g;
    int wrow = (brow < 128) ? (n0 + brow) : (H + n0 + brow - 128);
    bp[g] = W + (size_t)wrow * DMODEL + skc_s * 8;
  }

  f32x16 acc_a[2][2], acc_g[2][2];
  const f32x16 z16 = {0.f,0.f,0.f,0.f,0.f,0.f,0.f,0.f,0.f,0.f,0.f,0.f,0.f,0.f,0.f,0.f};
#pragma unroll
  for (int i = 0; i < 2; ++i)
#pragma unroll
    for (int j = 0; j < 2; ++j) { acc_a[i][j] = z16; acc_g[i][j] = z16; }

#define G1_STAGE(B, KB)                                                   \
  {                                                                       \
    _Pragma("unroll") for (int g = 0; g < 2; ++g)                         \
        gl_lds16(ap[g] + (KB), &As[(B) * 4096 + g * 2048 + wv * 512]);    \
    _Pragma("unroll") for (int g = 0; g < 4; ++g)                         \
        gl_lds16(bp[g] + (KB), &Bs[(B) * 8192 + g * 2048 + wv * 512]);    \
  }

  int buf = 0;
  G1_STAGE(0, 0)
  for (int kt = 0; kt < DMODEL / 32; ++kt) {
    asm volatile("s_waitcnt vmcnt(0)" ::: "memory");
    __builtin_amdgcn_s_barrier();
    if (kt + 1 < DMODEL / 32) { G1_STAGE(buf ^ 1, (kt + 1) * 32) }
#pragma unroll
    for (int ks = 0; ks < 2; ++ks) {
      const int ko = ks * 16 + hi * 8;
      const int ch = ko >> 3;
      bf16x8 aF[2], bA[2], bG[2];
#pragma unroll
      for (int i = 0; i < 2; ++i) {
        int r = wr * 64 + i * 32 + ln31;
        aF[i] = *(const bf16x8*)&As[buf * 4096 + r * 32 + ((ch ^ ((r >> 1) & 3)) << 3)];
      }
#pragma unroll
      for (int j = 0; j < 2; ++j) {
        int r = wc * 64 + j * 32 + ln31;
        bA[j] = *(const bf16x8*)&Bs[buf * 8192 + r * 32 + ((ch ^ ((r >> 1) & 3)) << 3)];
        int r2 = 128 + r;
        bG[j] = *(const bf16x8*)&Bs[buf * 8192 + r2 * 32 + ((ch ^ ((r2 >> 1) & 3)) << 3)];
      }
#pragma unroll
      for (int i = 0; i < 2; ++i)
#pragma unroll
        for (int j = 0; j < 2; ++j) {
          acc_a[i][j] = __builtin_amdgcn_mfma_f32_32x32x16_bf16(aF[i], bA[j], acc_a[i][j], 0, 0, 0);
          acc_g[i][j] = __builtin_amdgcn_mfma_f32_32x32x16_bf16(aF[i], bG[j], acc_g[i][j], 0, 0, 0);
        }
    }
    buf ^= 1;
  }
#undef G1_STAGE

  float ba[2], bg[2];
#pragma unroll
  for (int j = 0; j < 2; ++j) {
    int col = n0 + wc * 64 + j * 32 + ln31;
    ba[j] = bias[col];
    bg[j] = bias[H + col];
  }
#pragma unroll
  for (int i = 0; i < 2; ++i)
#pragma unroll
    for (int j = 0; j < 2; ++j)
#pragma unroll
      for (int reg = 0; reg < 16; ++reg) {
        // 32x32 C/D: col = lane&31, row = (reg&3) + 8*(reg>>2) + 4*(lane>>5)
        int row = wr * 64 + i * 32 + (reg & 3) + 8 * (reg >> 2) + 4 * hi;
        if (m0 + row < count) {
          int col = n0 + wc * 64 + j * 32 + ln31;
          float av = acc_a[i][j][reg] + ba[j];
          float gv = acc_g[i][j][reg] + bg[j];
          ACT[(size_t)(off + m0 + row) * H + col] = f2bf(av * gelu_exact(gv));
        }
      }
}

// ---------------- GEMM2, single launch (shared + routed), split-K ---------
// Split-K partials go to SP (shared, 2 splits) / YP (routed slot-space,
// 3 splits) via plain stores -- no atomics. combine_kernel sums + weights.
// Same BK=32 dbuf 2-phase + swizzle as gemm1. LDS 32 KB, VGPRs ~124 ->
// __launch_bounds__(256,4) for 4 blocks/CU residency.
#define G2_SHARED 256   /* 16 m x 8 n x 2 ksplit */
#define G2_PER_E  384   /* 16 m x 8 n x 3 ksplit */

__global__ __launch_bounds__(256, 4)
void gemm2_all_kernel(const unsigned short* __restrict__ ACT_S,
                      const unsigned short* __restrict__ ACT_R,
                      const unsigned short* __restrict__ WSt,
                      const unsigned short* __restrict__ WEt,
                      const float* __restrict__ BSb, const float* __restrict__ BEb,
                      float* __restrict__ SP, float* __restrict__ YP,
                      const int* __restrict__ offs, const int* __restrict__ counts) {
  int id = blockIdx.x;
  const unsigned short* A; const unsigned short* W; const float* bias;
  int K, count, off, m0, n0, routed, kc;
  if (id < G2_SHARED) {
    routed = 0;
    kc = id & 1;
    const int rem2 = id >> 1;
    m0 = (rem2 >> 3) * 128; n0 = (rem2 & 7) * 128;
    A = ACT_S; W = WSt; bias = BSb; K = HS_DIM; count = N_TOK; off = 0;
  } else {
    routed = 1;
    id -= G2_SHARED;
    const int e = id / G2_PER_E, rem = id % G2_PER_E;
    kc = rem % 3;
    const int rem2 = rem / 3;
    m0 = (rem2 >> 3) * 128; n0 = (rem2 & 7) * 128;
    A = ACT_R; W = WEt + (size_t)e * DMODEL * HR_DIM;
    bias = BEb + (size_t)e * DMODEL; K = HR_DIM; count = counts[e]; off = offs[e];
  }
  if (m0 >= count) return;

  // per buffer: A 128x32 shorts (8 KB), B 128x32 shorts (8 KB); x2 = 32 KB
  __shared__ __align__(16) unsigned short As[2 * 4096];
  __shared__ __align__(16) unsigned short Bs[2 * 4096];

  const int t = threadIdx.x;
  const int lane = t & 63, wv = t >> 6;
  const int srow = t >> 2, skc = t & 3;
  const int ln31 = lane & 31, hi = lane >> 5;
  const int wr = wv >> 1, wc = wv & 1;
  const int skc_s = skc ^ ((srow >> 1) & 3);

  const unsigned short* ap[2];
#pragma unroll
  for (int g = 0; g < 2; ++g) {
    int mr = m0 + srow + 64 * g;
    int r = off + (mr < count ? mr : count - 1);
    ap[g] = A + (size_t)r * K + skc_s * 8;
  }
  const unsigned short* bp[2];
#pragma unroll
  for (int g = 0; g < 2; ++g)
    bp[g] = W + (size_t)(n0 + srow + 64 * g) * K + skc_s * 8;

  f32x16 acc[2][2];
  const f32x16 z16 = {0.f,0.f,0.f,0.f,0.f,0.f,0.f,0.f,0.f,0.f,0.f,0.f,0.f,0.f,0.f,0.f};
#pragma unroll
  for (int i = 0; i < 2; ++i)
#pragma unroll
    for (int j = 0; j < 2; ++j) acc[i][j] = z16;

#define G2_STAGE(B, KB)                                                   \
  {                                                                       \
    _Pragma("unroll") for (int g = 0; g < 2; ++g) {                       \
      gl_lds16(ap[g] + (KB), &As[(B) * 4096 + g * 2048 + wv * 512]);      \
      gl_lds16(bp[g] + (KB), &Bs[(B) * 4096 + g * 2048 + wv * 512]);      \
    }                                                                     \
  }

  const int kb0 = kc * 1024;
  int buf = 0;
  G2_STAGE(0, kb0)
  for (int kt = 0; kt < 32; ++kt) {
    asm volatile("s_waitcnt vmcnt(0)" ::: "memory");
    __builtin_amdgcn_s_barrier();
    if (kt + 1 < 32) { G2_STAGE(buf ^ 1, kb0 + (kt + 1) * 32) }
#pragma unroll
    for (int ks = 0; ks < 2; ++ks) {
      const int ko = ks * 16 + hi * 8;
      const int ch = ko >> 3;
      bf16x8 aF[2], bF[2];
#pragma unroll
      for (int i = 0; i < 2; ++i) {
        int r = wr * 64 + i * 32 + ln31;
        aF[i] = *(const bf16x8*)&As[buf * 4096 + r * 32 + ((ch ^ ((r >> 1) & 3)) << 3)];
      }
#pragma unroll
      for (int j = 0; j < 2; ++j) {
        int r = wc * 64 + j * 32 + ln31;
        bF[j] = *(const bf16x8*)&Bs[buf * 4096 + r * 32 + ((ch ^ ((r >> 1) & 3)) << 3)];
      }
#pragma unroll
      for (int i = 0; i < 2; ++i)
#pragma unroll
        for (int j = 0; j < 2; ++j)
          acc[i][j] = __builtin_amdgcn_mfma_f32_32x32x16_bf16(aF[i], bF[j], acc[i][j], 0, 0, 0);
    }
    buf ^= 1;
  }
#undef G2_STAGE

  float bb[2];
#pragma unroll
  for (int j = 0; j < 2; ++j)
    bb[j] = (kc == 0) ? bias[n0 + wc * 64 + j * 32 + ln31] : 0.f;
#pragma unroll
  for (int i = 0; i < 2; ++i)
#pragma unroll
    for (int j = 0; j < 2; ++j)
#pragma unroll
      for (int reg = 0; reg < 16; ++reg) {
        int row = wr * 64 + i * 32 + (reg & 3) + 8 * (reg >> 2) + 4 * hi;
        if (m0 + row < count) {
          int col = n0 + wc * 64 + j * 32 + ln31;
          float v = acc[i][j][reg] + bb[j];
          if (routed) {
            YP[((size_t)kc * NSLOT + off + m0 + row) * DMODEL + col] = v;
          } else {
            SP[((size_t)kc * N_TOK + m0 + row) * DMODEL + col] = v;
          }
        }
      }
}

// ---------------- combine: out = SP0+SP1 + w0*SumYP(s0) + w1*SumYP(s1) ----
__global__ __launch_bounds__(256)
void combine_kernel(const float* __restrict__ SP, const float* __restrict__ YP,
                    const int* __restrict__ tok_slot, const float* __restrict__ slot_w,
                    float* __restrict__ OUT) {
  const int n = blockIdx.x;
  const int tx = threadIdx.x;
  const int s0 = tok_slot[n * 2 + 0], s1 = tok_slot[n * 2 + 1];
  const float w0 = slot_w[s0], w1 = slot_w[s1];
  float4 r = ((const float4*)(SP + (size_t)n * DMODEL))[tx];
  float4 b = ((const float4*)(SP + (size_t)(N_TOK + n) * DMODEL))[tx];
  r.x += b.x; r.y += b.y; r.z += b.z; r.w += b.w;
#pragma unroll
  for (int kc = 0; kc < 3; ++kc) {
    float4 p0 = ((const float4*)(YP + ((size_t)kc * NSLOT + s0) * DMODEL))[tx];
    float4 p1 = ((const float4*)(YP + ((size_t)kc * NSLOT + s1) * DMODEL))[tx];
    r.x += w0 * p0.x + w1 * p1.x;
    r.y += w0 * p0.y + w1 * p1.y;
    r.z += w0 * p0.z + w1 * p1.z;
    r.w += w0 * p0.w + w1 * p1.w;
  }
  ((float4*)(OUT + (size_t)n * DMODEL))[tx] = r;
}

// ---------------- launch ----------------

extern "C" void kernel_launch(void* const* d_in, const int* in_sizes, int n_in,
                              void* d_out, int out_size, void* d_ws, size_t ws_size,
                              hipStream_t stream) {
  const float* x   = (const float*)d_in[0];
  const float* Ws1 = (const float*)d_in[1];
  const float* bs1 = (const float*)d_in[2];
  const float* Ws2 = (const float*)d_in[3];
  const float* bs2 = (const float*)d_in[4];
  const float* We1 = (const float*)d_in[5];
  const float* be1 = (const float*)d_in[6];
  const float* We2 = (const float*)d_in[7];
  const float* be2 = (const float*)d_in[8];
  const float* Wr  = (const float*)d_in[9];
  const float* br  = (const float*)d_in[10];
  float* out = (float*)d_out;

  char* p = (char*)d_ws;
  int* counts  = (int*)p; p += 256;
  int* cursors = (int*)p; p += 256;
  int* offs    = (int*)p; p += 256;
  int* top_e   = (int*)p; p += (size_t)N_TOK * 2 * 4;
  float* top_w = (float*)p; p += (size_t)N_TOK * 2 * 4;
  int* slot_tok = (int*)p; p += (size_t)NSLOT * 4;
  float* slot_w = (float*)p; p += (size_t)NSLOT * 4;
  int* tok_slot = (int*)p; p += (size_t)N_TOK * 2 * 4;
  unsigned short* xb    = (unsigned short*)p; p += (size_t)N_TOK * DMODEL * 2;
  unsigned short* ws1t  = (unsigned short*)p; p += (size_t)2 * HS_DIM * DMODEL * 2;
  unsigned short* ws2t  = (unsigned short*)p; p += (size_t)DMODEL * HS_DIM * 2;
  unsigned short* we1t  = (unsigned short*)p; p += (size_t)NEXP * 2 * HR_DIM * DMODEL * 2;
  unsigned short* we2t  = (unsigned short*)p; p += (size_t)NEXP * DMODEL * HR_DIM * 2;
  unsigned short* act_s = (unsigned short*)p; p += (size_t)N_TOK * HS_DIM * 2;
  unsigned short* act_r = (unsigned short*)p; p += (size_t)NSLOT * HR_DIM * 2;
  float* sp = (float*)p; p += (size_t)2 * N_TOK * DMODEL * 4;   // 16 MB
  float* yp = (float*)p; p += (size_t)3 * NSLOT * DMODEL * 4;   // 48 MB

  // conversions
  convert_x_kernel<<<(N_TOK * DMODEL) / 2048, 256, 0, stream>>>(x, xb);
  tconv_kernel<<<dim3(2 * HS_DIM / 64, DMODEL / 64, 1), 256, 0, stream>>>(Ws1, ws1t, DMODEL, 2 * HS_DIM);
  tconv_kernel<<<dim3(DMODEL / 64, HS_DIM / 64, 1), 256, 0, stream>>>(Ws2, ws2t, HS_DIM, DMODEL);
  tconv_kernel<<<dim3(2 * HR_DIM / 64, DMODEL / 64, NEXP), 256, 0, stream>>>(We1, we1t, DMODEL, 2 * HR_DIM);
  tconv_kernel<<<dim3(DMODEL / 64, HR_DIM / 64, NEXP), 256, 0, stream>>>(We2, we2t, HR_DIM, DMODEL);

  // routing chain
  init_kernel<<<1, 64, 0, stream>>>(counts, cursors);
  router_kernel<<<N_TOK / 4, 256, 0, stream>>>(x, Wr, br, top_e, top_w, counts);
  scan_kernel<<<1, 64, 0, stream>>>(counts, offs);
  fill_kernel<<<N_TOK / 256, 256, 0, stream>>>(top_e, top_w, offs, cursors, slot_tok, slot_w, tok_slot);

  // GEMM1 + GEGLU (shared + all experts, one launch)
  gemm1_all_kernel<<<G1_SHARED + G1_PER_E * NEXP, 256, 0, stream>>>(
      xb, ws1t, we1t, bs1, be1, act_s, act_r, slot_tok, offs, counts);

  // GEMM2 (shared + routed, split-K, plain-store partials)
  gemm2_all_kernel<<<G2_SHARED + G2_PER_E * NEXP, 256, 0, stream>>>(
      act_s, act_r, ws2t, we2t, bs2, be2, sp, yp, offs, counts);

  // final combine (replaces atomics + zero_out)
  combine_kernel<<<N_TOK, 256, 0, stream>>>(sp, yp, tok_slot, slot_w, out);
}

// Round 3
// 836.580 us; speedup vs baseline: 1.1554x; 1.0643x over previous
//
#include <hip/hip_runtime.h>

#define N_TOK 2048
#define DMODEL 1024
#define NEXP 12
#define HS_DIM 2048
#define HR_DIM 3072
#define NSLOT (2 * N_TOK)   /* 4096 routed slots total */

typedef __attribute__((ext_vector_type(8))) short bf16x8;
typedef __attribute__((ext_vector_type(16))) float f32x16;

#define AS1 __attribute__((address_space(1)))
#define AS3 __attribute__((address_space(3)))

__device__ __forceinline__ void gl_lds16(const void* g, void* l) {
  __builtin_amdgcn_global_load_lds((const AS1 void*)g, (AS3 void*)l, 16, 0, 0);
}

__device__ __forceinline__ unsigned short f2bf(float x) {
  union { float f; unsigned int u; } v; v.f = x;
  unsigned int u = v.u;
  u += 0x7fff + ((u >> 16) & 1);   // round-to-nearest-even
  return (unsigned short)(u >> 16);
}
__device__ __forceinline__ unsigned pack2(float a, float b) {
  return (unsigned)f2bf(a) | ((unsigned)f2bf(b) << 16);
}
__device__ __forceinline__ float gelu_exact(float x) {
  return 0.5f * x * (1.0f + erff(x * 0.70710678118654752f));
}

// ---------------- device bodies ----------------

// W [K][N] fp32 tile (k0,n0) -> WT [N][K] bf16.  Ts = 64*72 shorts scratch.
__device__ __forceinline__ void tconv_body(const float* __restrict__ W,
                                           unsigned short* __restrict__ WT,
                                           int K, int N, int n0, int k0,
                                           unsigned short* Ts) {
  const int t = threadIdx.x;
  const int k4 = (t >> 4) * 4, n4 = (t & 15) * 4;
  float4 rw[4];
#pragma unroll
  for (int i = 0; i < 4; ++i)
    rw[i] = *(const float4*)(W + (size_t)(k0 + k4 + i) * N + n0 + n4);
#pragma unroll
  for (int j = 0; j < 4; ++j) {
    uint2 v;
    v.x = pack2(((const float*)&rw[0])[j], ((const float*)&rw[1])[j]);
    v.y = pack2(((const float*)&rw[2])[j], ((const float*)&rw[3])[j]);
    *(uint2*)&Ts[(n4 + j) * 72 + k4] = v;
  }
  __syncthreads();
  const int n = t >> 2, kc = (t & 3) * 16;
  uint4 v0 = *(const uint4*)&Ts[n * 72 + kc];
  uint4 v1 = *(const uint4*)&Ts[n * 72 + kc + 8];
  unsigned short* dst = WT + (size_t)(n0 + n) * K + k0 + kc;
  *(uint4*)dst = v0;
  *(uint4*)(dst + 8) = v1;
}

// GEMM1 + GEGLU body. BM=128, BN=128 act-cols (B panel 256 rows: a then g).
// BK=32 double-buffered, prefetch-next-before-compute, source-side chunk
// swizzle (skc ^ ((row>>1)&3)) mirrored on the ds_read side.
// As = 2*4096 shorts, Bs = 2*8192 shorts.
__device__ __forceinline__ void gemm1_body(
    const unsigned short* __restrict__ XB, const unsigned short* __restrict__ W,
    const float* __restrict__ bias, unsigned short* __restrict__ ACT,
    const int H, const int count, const int off, const int m0, const int n0,
    const int routed, const int* __restrict__ slot_tok,
    unsigned short* As, unsigned short* Bs) {
  const int t = threadIdx.x;
  const int lane = t & 63, wv = t >> 6;
  const int srow = t >> 2, skc = t & 3;
  const int ln31 = lane & 31, hi = lane >> 5;
  const int wr = wv >> 1, wc = wv & 1;
  const int skc_s = skc ^ ((srow >> 1) & 3);   // source-side chunk swizzle

  const unsigned short* ap[2];
#pragma unroll
  for (int g = 0; g < 2; ++g) {
    int mr = m0 + srow + 64 * g;
    int tok;
    if (routed) {
      int s = off + (mr < count ? mr : count - 1);
      tok = slot_tok[s];
    } else {
      tok = mr;
    }
    ap[g] = XB + (size_t)tok * DMODEL + skc_s * 8;
  }
  const unsigned short* bp[4];
#pragma unroll
  for (int g = 0; g < 4; ++g) {
    int brow = srow + 64 * g;
    int wrow = (brow < 128) ? (n0 + brow) : (H + n0 + brow - 128);
    bp[g] = W + (size_t)wrow * DMODEL + skc_s * 8;
  }

  f32x16 acc_a[2][2], acc_g[2][2];
  const f32x16 z16 = {0.f,0.f,0.f,0.f,0.f,0.f,0.f,0.f,0.f,0.f,0.f,0.f,0.f,0.f,0.f,0.f};
#pragma unroll
  for (int i = 0; i < 2; ++i)
#pragma unroll
    for (int j = 0; j < 2; ++j) { acc_a[i][j] = z16; acc_g[i][j] = z16; }

#define G1_STAGE(B, KB)                                                   \
  {                                                                       \
    _Pragma("unroll") for (int g = 0; g < 2; ++g)                         \
        gl_lds16(ap[g] + (KB), &As[(B) * 4096 + g * 2048 + wv * 512]);    \
    _Pragma("unroll") for (int g = 0; g < 4; ++g)                         \
        gl_lds16(bp[g] + (KB), &Bs[(B) * 8192 + g * 2048 + wv * 512]);    \
  }

  int buf = 0;
  G1_STAGE(0, 0)
  for (int kt = 0; kt < DMODEL / 32; ++kt) {
    asm volatile("s_waitcnt vmcnt(0)" ::: "memory");
    __builtin_amdgcn_s_barrier();
    if (kt + 1 < DMODEL / 32) { G1_STAGE(buf ^ 1, (kt + 1) * 32) }
#pragma unroll
    for (int ks = 0; ks < 2; ++ks) {
      const int ko = ks * 16 + hi * 8;
      const int ch = ko >> 3;
      bf16x8 aF[2], bA[2], bG[2];
#pragma unroll
      for (int i = 0; i < 2; ++i) {
        int r = wr * 64 + i * 32 + ln31;
        aF[i] = *(const bf16x8*)&As[buf * 4096 + r * 32 + ((ch ^ ((r >> 1) & 3)) << 3)];
      }
#pragma unroll
      for (int j = 0; j < 2; ++j) {
        int r = wc * 64 + j * 32 + ln31;
        bA[j] = *(const bf16x8*)&Bs[buf * 8192 + r * 32 + ((ch ^ ((r >> 1) & 3)) << 3)];
        int r2 = 128 + r;
        bG[j] = *(const bf16x8*)&Bs[buf * 8192 + r2 * 32 + ((ch ^ ((r2 >> 1) & 3)) << 3)];
      }
#pragma unroll
      for (int i = 0; i < 2; ++i)
#pragma unroll
        for (int j = 0; j < 2; ++j) {
          acc_a[i][j] = __builtin_amdgcn_mfma_f32_32x32x16_bf16(aF[i], bA[j], acc_a[i][j], 0, 0, 0);
          acc_g[i][j] = __builtin_amdgcn_mfma_f32_32x32x16_bf16(aF[i], bG[j], acc_g[i][j], 0, 0, 0);
        }
    }
    buf ^= 1;
  }
#undef G1_STAGE

  float ba[2], bg[2];
#pragma unroll
  for (int j = 0; j < 2; ++j) {
    int col = n0 + wc * 64 + j * 32 + ln31;
    ba[j] = bias[col];
    bg[j] = bias[H + col];
  }
#pragma unroll
  for (int i = 0; i < 2; ++i)
#pragma unroll
    for (int j = 0; j < 2; ++j)
#pragma unroll
      for (int reg = 0; reg < 16; ++reg) {
        // 32x32 C/D: col = lane&31, row = (reg&3) + 8*(reg>>2) + 4*(lane>>5)
        int row = wr * 64 + i * 32 + (reg & 3) + 8 * (reg >> 2) + 4 * hi;
        if (m0 + row < count) {
          int col = n0 + wc * 64 + j * 32 + ln31;
          float av = acc_a[i][j][reg] + ba[j];
          float gv = acc_g[i][j][reg] + bg[j];
          ACT[(size_t)(off + m0 + row) * H + col] = f2bf(av * gelu_exact(gv));
        }
      }
}

// ---------------- merged launches ----------------

// prep: convert_x [0,1024) | tconv Ws1 [1024,2048) | init [2048]
__global__ __launch_bounds__(256)
void prep_kernel(const float* __restrict__ X, unsigned short* __restrict__ XB,
                 const float* __restrict__ Ws1, unsigned short* __restrict__ WS1T,
                 int* __restrict__ counts, int* __restrict__ cursors) {
  __shared__ __align__(16) unsigned short Ts[64 * 72];
  const int id = blockIdx.x;
  const int t = threadIdx.x;
  if (id < 1024) {
    const int idx = (id * 256 + t) * 8;
    float4 f0 = *(const float4*)(X + idx);
    float4 f1 = *(const float4*)(X + idx + 4);
    uint4 o;
    o.x = pack2(f0.x, f0.y); o.y = pack2(f0.z, f0.w);
    o.z = pack2(f1.x, f1.y); o.w = pack2(f1.z, f1.w);
    *(uint4*)(XB + idx) = o;
  } else if (id < 2048) {
    const int tid = id - 1024;
    tconv_body(Ws1, WS1T, DMODEL, 2 * HS_DIM, (tid & 63) * 64, (tid >> 6) * 64, Ts);
  } else {
    if (t < NEXP) { counts[t] = 0; cursors[t] = 0; }
  }
}

// g1s: gemm1-shared [0,256) | tconv We1 [256,18688) | tconv Ws2 [18688,19200)
__global__ __launch_bounds__(256, 2)
void g1s_kernel(const unsigned short* __restrict__ XB,
                const unsigned short* __restrict__ WS,
                const float* __restrict__ BSb, unsigned short* __restrict__ ACT_S,
                const float* __restrict__ We1, unsigned short* __restrict__ WE1T,
                const float* __restrict__ Ws2, unsigned short* __restrict__ WS2T) {
  __shared__ __align__(16) unsigned short SMEM[24576];   // 48 KB arena
  const int id = blockIdx.x;
  if (id < 256) {
    gemm1_body(XB, WS, BSb, ACT_S, HS_DIM, N_TOK, 0,
               (id >> 4) * 128, (id & 15) * 128, 0, nullptr,
               SMEM, SMEM + 8192);
  } else if (id < 18688) {
    const int tid = id - 256;
    const int e = tid / 1536, rem = tid % 1536;
    tconv_body(We1 + (size_t)e * DMODEL * 2 * HR_DIM,
               WE1T + (size_t)e * 2 * HR_DIM * DMODEL,
               DMODEL, 2 * HR_DIM, (rem % 96) * 64, (rem / 96) * 64, SMEM);
  } else {
    const int tid = id - 18688;
    tconv_body(Ws2, WS2T, HS_DIM, DMODEL, (tid & 15) * 64, (tid >> 4) * 64, SMEM);
  }
}

// g1r: gemm1-routed [0,4608) | tconv We2 [4608,13824)
__global__ __launch_bounds__(256, 2)
void g1r_kernel(const unsigned short* __restrict__ XB,
                const unsigned short* __restrict__ WE1T,
                const float* __restrict__ BEb, unsigned short* __restrict__ ACT_R,
                const int* __restrict__ slot_tok, const int* __restrict__ offs,
                const int* __restrict__ counts,
                const float* __restrict__ We2, unsigned short* __restrict__ WE2T) {
  __shared__ __align__(16) unsigned short SMEM[24576];
  const int id = blockIdx.x;
  if (id < 4608) {
    const int e = id / 384, rem = id % 384;
    const int m0 = (rem / 24) * 128, n0 = (rem % 24) * 128;
    const int count = counts[e];
    if (m0 >= count) return;
    gemm1_body(XB, WE1T + (size_t)e * 2 * HR_DIM * DMODEL,
               BEb + (size_t)e * 2 * HR_DIM, ACT_R, HR_DIM, count, offs[e],
               m0, n0, 1, slot_tok, SMEM, SMEM + 8192);
  } else {
    const int tid = id - 4608;
    const int e = tid / 768, rem = tid % 768;
    tconv_body(We2 + (size_t)e * HR_DIM * DMODEL,
               WE2T + (size_t)e * DMODEL * HR_DIM,
               HR_DIM, DMODEL, (rem & 15) * 64, (rem >> 4) * 64, SMEM);
  }
}

// ---------------- routing ----------------

__global__ __launch_bounds__(256)
void router_kernel(const float* __restrict__ X, const float* __restrict__ Wr,
                   const float* __restrict__ br, int* __restrict__ top_e,
                   float* __restrict__ top_w, int* __restrict__ counts) {
  const int wv = threadIdx.x >> 6, lane = threadIdx.x & 63;
  const int n = blockIdx.x * 4 + wv;
  float a[NEXP];
#pragma unroll
  for (int e = 0; e < NEXP; ++e) a[e] = 0.f;
  for (int it = 0; it < DMODEL / 64; ++it) {
    int k = it * 64 + lane;
    float xv = X[(size_t)n * DMODEL + k];
    const float* wr = Wr + (size_t)k * NEXP;
#pragma unroll
    for (int e = 0; e < NEXP; ++e) a[e] += xv * wr[e];
  }
#pragma unroll
  for (int e = 0; e < NEXP; ++e)
    for (int o = 32; o > 0; o >>= 1) a[e] += __shfl_xor(a[e], o, 64);
  if (lane == 0) {
    float l[NEXP];
#pragma unroll
    for (int e = 0; e < NEXP; ++e) l[e] = (a[e] + br[e]) * (1.0f / 1.5f);
    int e0 = 0;
    for (int e = 1; e < NEXP; ++e) if (l[e] > l[e0]) e0 = e;
    int e1 = (e0 == 0) ? 1 : 0;
    for (int e = 0; e < NEXP; ++e) if (e != e0 && l[e] > l[e1]) e1 = e;
    float w0 = 1.f / (1.f + expf(l[e1] - l[e0]));
    top_e[n * 2 + 0] = e0; top_e[n * 2 + 1] = e1;
    top_w[n * 2 + 0] = w0; top_w[n * 2 + 1] = 1.f - w0;
    atomicAdd(&counts[e0], 1); atomicAdd(&counts[e1], 1);
  }
}

__global__ void scan_kernel(const int* __restrict__ counts, int* __restrict__ offs) {
  if (threadIdx.x == 0) {
    int s = 0;
    for (int e = 0; e < NEXP; ++e) { offs[e] = s; s += counts[e]; }
    offs[NEXP] = s;
  }
}

__global__ __launch_bounds__(256)
void fill_kernel(const int* __restrict__ top_e, const float* __restrict__ top_w,
                 const int* __restrict__ offs, int* __restrict__ cursors,
                 int* __restrict__ slot_tok, float* __restrict__ slot_w,
                 int* __restrict__ tok_slot) {
  int n = blockIdx.x * 256 + threadIdx.x;
  if (n >= N_TOK) return;
#pragma unroll
  for (int j = 0; j < 2; ++j) {
    int e = top_e[n * 2 + j];
    int p = atomicAdd(&cursors[e], 1);
    int s = offs[e] + p;
    slot_tok[s] = n;
    slot_w[s] = top_w[n * 2 + j];
    tok_slot[n * 2 + j] = s;
  }
}

// ---------------- GEMM2, single launch (shared + routed), split-K ---------
#define G2_SHARED 256   /* 16 m x 8 n x 2 ksplit */
#define G2_PER_E  384   /* 16 m x 8 n x 3 ksplit */

__global__ __launch_bounds__(256, 4)
void gemm2_all_kernel(const unsigned short* __restrict__ ACT_S,
                      const unsigned short* __restrict__ ACT_R,
                      const unsigned short* __restrict__ WSt,
                      const unsigned short* __restrict__ WEt,
                      const float* __restrict__ BSb, const float* __restrict__ BEb,
                      float* __restrict__ SP, float* __restrict__ YP,
                      const int* __restrict__ offs, const int* __restrict__ counts) {
  int id = blockIdx.x;
  const unsigned short* A; const unsigned short* W; const float* bias;
  int K, count, off, m0, n0, routed, kc;
  if (id < G2_SHARED) {
    routed = 0;
    kc = id & 1;
    const int rem2 = id >> 1;
    m0 = (rem2 >> 3) * 128; n0 = (rem2 & 7) * 128;
    A = ACT_S; W = WSt; bias = BSb; K = HS_DIM; count = N_TOK; off = 0;
  } else {
    routed = 1;
    id -= G2_SHARED;
    const int e = id / G2_PER_E, rem = id % G2_PER_E;
    kc = rem % 3;
    const int rem2 = rem / 3;
    m0 = (rem2 >> 3) * 128; n0 = (rem2 & 7) * 128;
    A = ACT_R; W = WEt + (size_t)e * DMODEL * HR_DIM;
    bias = BEb + (size_t)e * DMODEL; K = HR_DIM; count = counts[e]; off = offs[e];
  }
  if (m0 >= count) return;

  __shared__ __align__(16) unsigned short As[2 * 4096];
  __shared__ __align__(16) unsigned short Bs[2 * 4096];

  const int t = threadIdx.x;
  const int lane = t & 63, wv = t >> 6;
  const int srow = t >> 2, skc = t & 3;
  const int ln31 = lane & 31, hi = lane >> 5;
  const int wr = wv >> 1, wc = wv & 1;
  const int skc_s = skc ^ ((srow >> 1) & 3);

  const unsigned short* ap[2];
#pragma unroll
  for (int g = 0; g < 2; ++g) {
    int mr = m0 + srow + 64 * g;
    int r = off + (mr < count ? mr : count - 1);
    ap[g] = A + (size_t)r * K + skc_s * 8;
  }
  const unsigned short* bp[2];
#pragma unroll
  for (int g = 0; g < 2; ++g)
    bp[g] = W + (size_t)(n0 + srow + 64 * g) * K + skc_s * 8;

  f32x16 acc[2][2];
  const f32x16 z16 = {0.f,0.f,0.f,0.f,0.f,0.f,0.f,0.f,0.f,0.f,0.f,0.f,0.f,0.f,0.f,0.f};
#pragma unroll
  for (int i = 0; i < 2; ++i)
#pragma unroll
    for (int j = 0; j < 2; ++j) acc[i][j] = z16;

#define G2_STAGE(B, KB)                                                   \
  {                                                                       \
    _Pragma("unroll") for (int g = 0; g < 2; ++g) {                       \
      gl_lds16(ap[g] + (KB), &As[(B) * 4096 + g * 2048 + wv * 512]);      \
      gl_lds16(bp[g] + (KB), &Bs[(B) * 4096 + g * 2048 + wv * 512]);      \
    }                                                                     \
  }

  const int kb0 = kc * 1024;
  int buf = 0;
  G2_STAGE(0, kb0)
  for (int kt = 0; kt < 32; ++kt) {
    asm volatile("s_waitcnt vmcnt(0)" ::: "memory");
    __builtin_amdgcn_s_barrier();
    if (kt + 1 < 32) { G2_STAGE(buf ^ 1, kb0 + (kt + 1) * 32) }
#pragma unroll
    for (int ks = 0; ks < 2; ++ks) {
      const int ko = ks * 16 + hi * 8;
      const int ch = ko >> 3;
      bf16x8 aF[2], bF[2];
#pragma unroll
      for (int i = 0; i < 2; ++i) {
        int r = wr * 64 + i * 32 + ln31;
        aF[i] = *(const bf16x8*)&As[buf * 4096 + r * 32 + ((ch ^ ((r >> 1) & 3)) << 3)];
      }
#pragma unroll
      for (int j = 0; j < 2; ++j) {
        int r = wc * 64 + j * 32 + ln31;
        bF[j] = *(const bf16x8*)&Bs[buf * 4096 + r * 32 + ((ch ^ ((r >> 1) & 3)) << 3)];
      }
#pragma unroll
      for (int i = 0; i < 2; ++i)
#pragma unroll
        for (int j = 0; j < 2; ++j)
          acc[i][j] = __builtin_amdgcn_mfma_f32_32x32x16_bf16(aF[i], bF[j], acc[i][j], 0, 0, 0);
    }
    buf ^= 1;
  }
#undef G2_STAGE

  float bb[2];
#pragma unroll
  for (int j = 0; j < 2; ++j)
    bb[j] = (kc == 0) ? bias[n0 + wc * 64 + j * 32 + ln31] : 0.f;
#pragma unroll
  for (int i = 0; i < 2; ++i)
#pragma unroll
    for (int j = 0; j < 2; ++j)
#pragma unroll
      for (int reg = 0; reg < 16; ++reg) {
        int row = wr * 64 + i * 32 + (reg & 3) + 8 * (reg >> 2) + 4 * hi;
        if (m0 + row < count) {
          int col = n0 + wc * 64 + j * 32 + ln31;
          float v = acc[i][j][reg] + bb[j];
          if (routed) {
            YP[((size_t)kc * NSLOT + off + m0 + row) * DMODEL + col] = v;
          } else {
            SP[((size_t)kc * N_TOK + m0 + row) * DMODEL + col] = v;
          }
        }
      }
}

// ---------------- combine: out = SP0+SP1 + w0*SumYP(s0) + w1*SumYP(s1) ----
__global__ __launch_bounds__(256)
void combine_kernel(const float* __restrict__ SP, const float* __restrict__ YP,
                    const int* __restrict__ tok_slot, const float* __restrict__ slot_w,
                    float* __restrict__ OUT) {
  const int n = blockIdx.x;
  const int tx = threadIdx.x;
  const int s0 = tok_slot[n * 2 + 0], s1 = tok_slot[n * 2 + 1];
  const float w0 = slot_w[s0], w1 = slot_w[s1];
  float4 r = ((const float4*)(SP + (size_t)n * DMODEL))[tx];
  float4 b = ((const float4*)(SP + (size_t)(N_TOK + n) * DMODEL))[tx];
  r.x += b.x; r.y += b.y; r.z += b.z; r.w += b.w;
#pragma unroll
  for (int kc = 0; kc < 3; ++kc) {
    float4 p0 = ((const float4*)(YP + ((size_t)kc * NSLOT + s0) * DMODEL))[tx];
    float4 p1 = ((const float4*)(YP + ((size_t)kc * NSLOT + s1) * DMODEL))[tx];
    r.x += w0 * p0.x + w1 * p1.x;
    r.y += w0 * p0.y + w1 * p1.y;
    r.z += w0 * p0.z + w1 * p1.z;
    r.w += w0 * p0.w + w1 * p1.w;
  }
  ((float4*)(OUT + (size_t)n * DMODEL))[tx] = r;
}

// ---------------- launch ----------------

extern "C" void kernel_launch(void* const* d_in, const int* in_sizes, int n_in,
                              void* d_out, int out_size, void* d_ws, size_t ws_size,
                              hipStream_t stream) {
  const float* x   = (const float*)d_in[0];
  const float* Ws1 = (const float*)d_in[1];
  const float* bs1 = (const float*)d_in[2];
  const float* Ws2 = (const float*)d_in[3];
  const float* bs2 = (const float*)d_in[4];
  const float* We1 = (const float*)d_in[5];
  const float* be1 = (const float*)d_in[6];
  const float* We2 = (const float*)d_in[7];
  const float* be2 = (const float*)d_in[8];
  const float* Wr  = (const float*)d_in[9];
  const float* br  = (const float*)d_in[10];
  float* out = (float*)d_out;

  char* p = (char*)d_ws;
  int* counts  = (int*)p; p += 256;
  int* cursors = (int*)p; p += 256;
  int* offs    = (int*)p; p += 256;
  int* top_e   = (int*)p; p += (size_t)N_TOK * 2 * 4;
  float* top_w = (float*)p; p += (size_t)N_TOK * 2 * 4;
  int* slot_tok = (int*)p; p += (size_t)NSLOT * 4;
  float* slot_w = (float*)p; p += (size_t)NSLOT * 4;
  int* tok_slot = (int*)p; p += (size_t)N_TOK * 2 * 4;
  unsigned short* xb    = (unsigned short*)p; p += (size_t)N_TOK * DMODEL * 2;
  unsigned short* ws1t  = (unsigned short*)p; p += (size_t)2 * HS_DIM * DMODEL * 2;
  unsigned short* ws2t  = (unsigned short*)p; p += (size_t)DMODEL * HS_DIM * 2;
  unsigned short* we1t  = (unsigned short*)p; p += (size_t)NEXP * 2 * HR_DIM * DMODEL * 2;
  unsigned short* we2t  = (unsigned short*)p; p += (size_t)NEXP * DMODEL * HR_DIM * 2;
  unsigned short* act_s = (unsigned short*)p; p += (size_t)N_TOK * HS_DIM * 2;
  unsigned short* act_r = (unsigned short*)p; p += (size_t)NSLOT * HR_DIM * 2;
  float* sp = (float*)p; p += (size_t)2 * N_TOK * DMODEL * 4;   // 16 MB
  float* yp = (float*)p; p += (size_t)3 * NSLOT * DMODEL * 4;   // 48 MB

  // prep: x->bf16 | Ws1 transpose | counts/cursors init
  prep_kernel<<<2049, 256, 0, stream>>>(x, xb, Ws1, ws1t, counts, cursors);

  // routing chain
  router_kernel<<<N_TOK / 4, 256, 0, stream>>>(x, Wr, br, top_e, top_w, counts);
  scan_kernel<<<1, 64, 0, stream>>>(counts, offs);
  fill_kernel<<<N_TOK / 256, 256, 0, stream>>>(top_e, top_w, offs, cursors, slot_tok, slot_w, tok_slot);

  // gemm1-shared || tconv(We1) || tconv(Ws2)
  g1s_kernel<<<19200, 256, 0, stream>>>(xb, ws1t, bs1, act_s, We1, we1t, Ws2, ws2t);

  // gemm1-routed || tconv(We2)
  g1r_kernel<<<13824, 256, 0, stream>>>(xb, we1t, be1, act_r, slot_tok, offs, counts, We2, we2t);

  // GEMM2 (shared + routed, split-K, plain-store partials)
  gemm2_all_kernel<<<G2_SHARED + G2_PER_E * NEXP, 256, 0, stream>>>(
      act_s, act_r, ws2t, we2t, bs2, be2, sp, yp, offs, counts);

  // final combine
  combine_kernel<<<N_TOK, 256, 0, stream>>>(sp, yp, tok_slot, slot_w, out);
}